// Round 13
// baseline (159.990 us; speedup 1.0000x reference)
//
#include <hip/hip_runtime.h>

#define N_NODES 100000
#define N_EDGES 1600000
#define IN_F 128
#define OUT_F 64

#define BROWS 64               // rows per bucket (ceil(100000/64) = 1563 buckets)
#define NBUCKET 1563
#define BK_PAD 136             // padded k-stride (shorts) for b_lds: breaks 16-way bank repeat

#define NCHUNK 512             // edge chunks; sort LDS = 31.3 KB -> 5 blocks/CU
#define EPC (N_EDGES / NCHUNK) // 3125 edges per chunk (exact)
#define NPOS (NBUCKET + 1)     // 1564: per-chunk prefix incl. sentinel
#define GEMM_BLKS ((N_NODES + 127) / 128)   // 782: gemm sub-blocks (128 rows each)

#define SLOTS 40               // per-row segment capacity (mean 16, P(>40) ~ 4e-8)
#define NSPILL 128             // spill list (insurance)

typedef __attribute__((ext_vector_type(8))) short bf16x8;
typedef __attribute__((ext_vector_type(4))) float f32x4;

__device__ __forceinline__ unsigned short f32_to_bf16(float f) {
    const unsigned int b = __float_as_uint(f);
    return (unsigned short)((b + 0x7FFFu + ((b >> 16) & 1u)) >> 16);   // RNE
}
__device__ __forceinline__ float bf16_to_f32(unsigned short u) {
    return __uint_as_float(((unsigned int)u) << 16);
}
// unpack low/high bf16 of a uint32 (1 VALU each)
__device__ __forceinline__ float bflo(unsigned int u) { return __uint_as_float(u << 16); }
__device__ __forceinline__ float bfhi(unsigned int u) { return __uint_as_float(u & 0xFFFF0000u); }

// ---------------- Kernel 1: FUSED  gemm (blocks >= NCHUNK) + chunk-sort (blocks < NCHUNK) ----
// Staged coalesced sedge writes (r5/r6 lesson: beats direct scatter) at full occupancy:
// sd 25 KB + pos 6.3 KB (64-row buckets -> 1564 counters) = 31.3 KB union -> 5 blocks/CU.
//
// gemm: 512 thr = 8 waves; wave = 16 rows x 64 cols via MFMA 16x16x32 bf16. W transposed
// in LDS as [n][k] bf16 (pad 136) -> b-frags are ds_read_b128. Frag layouts
// (m89/m91-verified): A: m=lane&15,k=quad*8+j. B: n=lane&15,k=quad*8+j.
// C/D: col=lane&15, row=quad*4+r.
__global__ __launch_bounds__(512) void gemm_sort_kernel(
    const float* __restrict__ x, const float* __restrict__ w,
    unsigned short* __restrict__ support,
    const int* __restrict__ erow, const int* __restrict__ ecol,
    const float* __restrict__ evals, int* __restrict__ pos_g,
    uint2* __restrict__ sedge) {
    __shared__ union {
        struct { uint2 sd[EPC]; int pos[NPOS]; int wofs[8]; } s;   // 31.3 KB (sort)
        unsigned short b[OUT_F * BK_PAD];                          // 17.4 KB (gemm)
    } u;

    const int t = threadIdx.x;

    if (blockIdx.x < NCHUNK) {
        // ================= sort branch =================
        int* pos = u.s.pos;
        uint2* sd = u.s.sd;
        const int c = blockIdx.x;
        const size_t e0 = (size_t)c * EPC;

        for (int i = t; i < NPOS; i += 512) pos[i] = 0;
        __syncthreads();

        // pass 1: histogram over 64-row buckets (erow re-read in pass 2 is L2-hot)
        #pragma unroll 1
        for (int j = t; j < EPC; j += 512)
            atomicAdd(&pos[erow[e0 + j] >> 6], 1);
        __syncthreads();

        // block-exclusive scan over 1563 buckets, 4 per thread (512*4 = 2048 >= 1564)
        int v[4]; int s = 0;
        #pragma unroll
        for (int j = 0; j < 4; ++j) {
            const int i = t * 4 + j;
            v[j] = (i < NBUCKET) ? pos[i] : 0;
            s += v[j];
        }
        const int lane = t & 63, wid = t >> 6;
        int incl = s;
        #pragma unroll
        for (int d = 1; d < 64; d <<= 1) { int tv = __shfl_up(incl, d); if (lane >= d) incl += tv; }
        if (lane == 63) u.s.wofs[wid] = incl;
        __syncthreads();
        int wbase = 0;
        #pragma unroll
        for (int wj = 0; wj < 8; ++wj) wbase += (wj < wid) ? u.s.wofs[wj] : 0;
        int ex = wbase + incl - s;
        #pragma unroll
        for (int j = 0; j < 4; ++j) {
            const int i = t * 4 + j;
            if (i < NBUCKET) { pos[i] = ex; ex += v[j]; }   // own indices only: no hazard
        }
        if (t == 0) pos[NBUCKET] = EPC;
        __syncthreads();

        // persist per-chunk prefix (coalesced); gather reads it directly (L2-resident)
        int* pg = pos_g + (size_t)c * NPOS;
        for (int i = t; i < NPOS; i += 512) pg[i] = pos[i];
        __syncthreads();   // persist reads must finish before cursors mutate

        // pass 2: rank + scatter to LDS staging
        #pragma unroll 1
        for (int j = t; j < EPC; j += 512) {
            const int row = erow[e0 + j];
            const int col = ecol[e0 + j];
            const float val = evals[e0 + j];
            const int r = atomicAdd(&pos[row >> 6], 1);
            uint2 ed;
            ed.x = (unsigned int)col | (((unsigned int)row & 63u) << 20);
            ed.y = __float_as_uint(val);
            sd[r] = ed;
        }
        __syncthreads();

        // write sorted chunk, fully coalesced
        uint2* sg = sedge + e0;
        for (int i = t; i < EPC; i += 512) sg[i] = sd[i];
        return;
    }

    // ================= gemm branch =================
    const int bb = blockIdx.x - NCHUNK;
    // stage W transposed: w[k][n] (fp32, coalesced float4) -> b[n*BK_PAD + k] (bf16)
    #pragma unroll
    for (int i = 0; i < 4; ++i) {
        const int f = t + 512 * i;            // float4 index; k = f>>4, n4 = (f&15)*4
        const int k = f >> 4, n4 = (f & 15) * 4;
        const float4 wv = ((const float4*)w)[f];
        u.b[(n4 + 0) * BK_PAD + k] = f32_to_bf16(wv.x);
        u.b[(n4 + 1) * BK_PAD + k] = f32_to_bf16(wv.y);
        u.b[(n4 + 2) * BK_PAD + k] = f32_to_bf16(wv.z);
        u.b[(n4 + 3) * BK_PAD + k] = f32_to_bf16(wv.w);
    }
    __syncthreads();

    const int lane = t & 63, wid = t >> 6;
    const int m16 = lane & 15, quad = lane >> 4;
    const int row0 = bb * 128 + wid * 16;
    const int arow = min(row0 + m16, N_NODES - 1);
    const float* xr = x + (size_t)arow * IN_F;

    f32x4 acc[4];
    #pragma unroll
    for (int nt = 0; nt < 4; ++nt) acc[nt] = (f32x4){0.f, 0.f, 0.f, 0.f};

    #pragma unroll
    for (int kt = 0; kt < 4; ++kt) {
        const int kb = kt * 32 + quad * 8;
        const float4 a0 = *(const float4*)(xr + kb);
        const float4 a1 = *(const float4*)(xr + kb + 4);
        bf16x8 af;
        af[0] = (short)f32_to_bf16(a0.x); af[1] = (short)f32_to_bf16(a0.y);
        af[2] = (short)f32_to_bf16(a0.z); af[3] = (short)f32_to_bf16(a0.w);
        af[4] = (short)f32_to_bf16(a1.x); af[5] = (short)f32_to_bf16(a1.y);
        af[6] = (short)f32_to_bf16(a1.z); af[7] = (short)f32_to_bf16(a1.w);
        #pragma unroll
        for (int nt = 0; nt < 4; ++nt) {
            const bf16x8 bf = *(const bf16x8*)&u.b[(nt * 16 + m16) * BK_PAD + kb];
            acc[nt] = __builtin_amdgcn_mfma_f32_16x16x32_bf16(af, bf, acc[nt], 0, 0, 0);
        }
    }

    #pragma unroll
    for (int nt = 0; nt < 4; ++nt) {
        #pragma unroll
        for (int r = 0; r < 4; ++r) {
            const int row = row0 + quad * 4 + r;
            if (row < N_NODES)
                support[(size_t)row * OUT_F + nt * 16 + m16] = f32_to_bf16(acc[nt][r]);
        }
    }
}

// place one edge into its row segment
#define PLACE(ED) do { \
    const int r_ = ((ED).x >> 20) & 63; \
    const int sl_ = atomicAdd(&rcnt[r_], 1); \
    if (sl_ < SLOTS) sdata[r_ * SLOTS + sl_] = (ED); \
    else { const int q_ = atomicAdd(&nspill, 1); if (q_ < NSPILL) spill[q_] = (ED); } \
} while (0)

// one octet-batch: edge (B*8+eg) of row segment s0, 16 B (8 cols) per lane
#define OCT_LOAD(QB, B) \
    const uint2 QB = sdata[((B) * 8 + eg) < cnt ? s0 + (B) * 8 + eg : s0];
#define OCT_GATHER(HB, QB) \
    const uint4 HB = *(const uint4*)(support + (size_t)((QB).x & 0xFFFFFu) * OUT_F + c8 * 8);
#define OCT_FMA(QB, HB, B) do { \
    const float w_ = ((B) * 8 + eg) < cnt ? __uint_as_float((QB).y) : 0.f; \
    a0 += w_ * bflo((HB).x); a1 += w_ * bfhi((HB).x); \
    a2 += w_ * bflo((HB).y); a3 += w_ * bfhi((HB).y); \
    a4 += w_ * bflo((HB).z); a5 += w_ * bfhi((HB).z); \
    a6 += w_ * bflo((HB).w); a7 += w_ * bfhi((HB).w); \
} while (0)

// ---------------- Kernel 2: gather = one-pass segment placement + accumulation ---------------
// Back-end reshaped 8B->16B per lane (r11 lesson: issue-bound, not round-trip-bound):
// 8 edge-groups x 8 lanes x 8 cols/lane (uint4 support read). One octet-batch = 8
// edges in 1 LDS read + 1 gather; tiers 2/4/5 octets cover cnt<=16 (54% of rows) /
// <=32 (97%) / <=40 (=SLOTS, 100%) with wave-uniform branches -> HALF the VMEM
// instructions of r11 at the mean, no tail loop at all. Reduce: 3-level shfl_xor
// (8,16,32); eg==0 lanes store 2x float4. __launch_bounds__(512,8) pins VGPR<=64
// (4 blocks/CU). Front-end unchanged (proven r10): 4-deep batched run head.
// Bijective XCD swizzle (1563 = 8*195+3) for sedge/pos_g L2 locality.
__global__ __launch_bounds__(512, 8) void gather_kernel(
    const unsigned short* __restrict__ support, const uint2* __restrict__ sedge,
    const int* __restrict__ pos_g, const float* __restrict__ bias,
    float* __restrict__ out) {
    __shared__ uint2 sdata[BROWS * SLOTS];   // 20.5 KB row segments
    __shared__ uint2 spill[NSPILL];          // 1 KB (statistically never used)
    __shared__ int rcnt[BROWS];
    __shared__ int nspill;

    const int t = threadIdx.x;
    // nwg = 1563 = 8*195 + 3: xcd<3 owns 196 buckets, else 195 (bijective, m204)
    const int orig = blockIdx.x;
    const int xcd = orig & 7, loc = orig >> 3;
    const int k = (xcd < 3 ? xcd * 196 : 3 * 196 + (xcd - 3) * 195) + loc;
    const int lane = t & 63, wid = t >> 6;

    if (t < BROWS) rcnt[t] = 0;
    if (t == 0) nspill = 0;
    __syncthreads();

    // one-pass placement: thread t owns chunk t (pos_g[t][k], pos_g[t][k+1] share a
    // cache line; pos_g 3.2 MB -> L2-resident). 4-deep batched load head.
    {
        const int s = pos_g[(size_t)t * NPOS + k];
        const int e = pos_g[(size_t)t * NPOS + k + 1];
        const int L = e - s;
        const uint2* run = sedge + (size_t)t * EPC;
        uint2 b0, b1, b2, b3;
        if (L > 0) b0 = run[s];
        if (L > 1) b1 = run[s + 1];
        if (L > 2) b2 = run[s + 2];
        if (L > 3) b3 = run[s + 3];
        if (L > 0) PLACE(b0);
        if (L > 1) PLACE(b1);
        if (L > 2) PLACE(b2);
        if (L > 3) PLACE(b3);
        #pragma unroll 1
        for (int j = s + 4; j < e; j += 2) {     // rare tail (P ~ 5%), 2-deep
            uint2 c0 = run[j]; uint2 c1;
            const bool h2 = (j + 1) < e;
            if (h2) c1 = run[j + 1];
            PLACE(c0);
            if (h2) PLACE(c1);
        }
    }
    __syncthreads();

    const int eg = lane >> 3;          // edge-group 0..7
    const int c8 = lane & 7;           // col-octet: cols 8*c8 .. 8*c8+7
    const float4 bbA = ((const float4*)bias)[c8 * 2];
    const float4 bbB = ((const float4*)bias)[c8 * 2 + 1];

    for (int r8i = 0; r8i < 8; ++r8i) {
        const int r = wid * 8 + r8i;
        const int cnt = min(rcnt[r], SLOTS);
        const int s0 = r * SLOTS;
        float a0 = 0.f, a1 = 0.f, a2 = 0.f, a3 = 0.f;
        float a4 = 0.f, a5 = 0.f, a6 = 0.f, a7 = 0.f;
        if (cnt > 0) {                 // wave-uniform (all lanes share r)
            // tier 2: octets 0,1 (cnt <= 16 — 54% of rows stop here)
            OCT_LOAD(q0, 0); OCT_LOAD(q1, 1);
            OCT_GATHER(h0, q0); OCT_GATHER(h1, q1);
            OCT_FMA(q0, h0, 0); OCT_FMA(q1, h1, 1);
            if (cnt > 16) {
                // tier 4: octets 2,3 (cnt <= 32 — 97% cumulative)
                OCT_LOAD(q2, 2); OCT_LOAD(q3, 3);
                OCT_GATHER(h2, q2); OCT_GATHER(h3, q3);
                OCT_FMA(q2, h2, 2); OCT_FMA(q3, h3, 3);
                if (cnt > 32) {
                    // tier 5: octet 4 (cnt <= 40 = SLOTS — 100%)
                    OCT_LOAD(q4, 4);
                    OCT_GATHER(h4, q4);
                    OCT_FMA(q4, h4, 4);
                }
            }
        }
        // reduce over the 8 edge-groups (lane bits 3..5)
        a0 += __shfl_xor(a0, 8); a0 += __shfl_xor(a0, 16); a0 += __shfl_xor(a0, 32);
        a1 += __shfl_xor(a1, 8); a1 += __shfl_xor(a1, 16); a1 += __shfl_xor(a1, 32);
        a2 += __shfl_xor(a2, 8); a2 += __shfl_xor(a2, 16); a2 += __shfl_xor(a2, 32);
        a3 += __shfl_xor(a3, 8); a3 += __shfl_xor(a3, 16); a3 += __shfl_xor(a3, 32);
        a4 += __shfl_xor(a4, 8); a4 += __shfl_xor(a4, 16); a4 += __shfl_xor(a4, 32);
        a5 += __shfl_xor(a5, 8); a5 += __shfl_xor(a5, 16); a5 += __shfl_xor(a5, 32);
        a6 += __shfl_xor(a6, 8); a6 += __shfl_xor(a6, 16); a6 += __shfl_xor(a6, 32);
        a7 += __shfl_xor(a7, 8); a7 += __shfl_xor(a7, 16); a7 += __shfl_xor(a7, 32);
        const int node = k * BROWS + r;
        if (eg == 0 && node < N_NODES) {         // last bucket has 32 valid rows
            float4 oA, oB;
            oA.x = a0 + bbA.x; oA.y = a1 + bbA.y; oA.z = a2 + bbA.z; oA.w = a3 + bbA.w;
            oB.x = a4 + bbB.x; oB.y = a5 + bbB.y; oB.z = a6 + bbB.z; oB.w = a7 + bbB.w;
            float* op = out + (size_t)node * OUT_F + c8 * 8;
            *(float4*)op = oA;
            *(float4*)(op + 4) = oB;
        }
    }

    if (nspill > 0) {   // insurance: rows with >SLOTS edges (P ~ 4e-8 per row)
        __syncthreads();                       // out stores drained (vmcnt@barrier)
        const int ns = min(nspill, NSPILL);
        for (int i = wid; i < ns; i += 8) {    // wave per edge, lane = column
            const uint2 ed = spill[i];
            const float g = bf16_to_f32(support[(size_t)(ed.x & 0xFFFFFu) * OUT_F + lane]);
            atomicAdd(&out[(size_t)(k * BROWS + ((ed.x >> 20) & 63)) * OUT_F + lane],
                      g * __uint_as_float(ed.y));
        }
    }
}

// ---------------- Fallback (ws too small): gemm-only + bias-init + atomic scatter ----------
__global__ __launch_bounds__(256) void gemm_kernel(
    const float* __restrict__ x, const float* __restrict__ w,
    unsigned short* __restrict__ support) {
    __shared__ unsigned short b_lds[OUT_F * BK_PAD];
    const int t = threadIdx.x;
    #pragma unroll
    for (int i = 0; i < 8; ++i) {
        const int f = t + 256 * i;
        const int k = f >> 4, n4 = (f & 15) * 4;
        const float4 wv = ((const float4*)w)[f];
        b_lds[(n4 + 0) * BK_PAD + k] = f32_to_bf16(wv.x);
        b_lds[(n4 + 1) * BK_PAD + k] = f32_to_bf16(wv.y);
        b_lds[(n4 + 2) * BK_PAD + k] = f32_to_bf16(wv.z);
        b_lds[(n4 + 3) * BK_PAD + k] = f32_to_bf16(wv.w);
    }
    __syncthreads();
    const int lane = t & 63, wid = t >> 6;
    const int m16 = lane & 15, quad = lane >> 4;
    const int row0 = blockIdx.x * 64 + wid * 16;
    const int arow = min(row0 + m16, N_NODES - 1);
    const float* xr = x + (size_t)arow * IN_F;
    f32x4 acc[4];
    #pragma unroll
    for (int nt = 0; nt < 4; ++nt) acc[nt] = (f32x4){0.f, 0.f, 0.f, 0.f};
    #pragma unroll
    for (int kt = 0; kt < 4; ++kt) {
        const int kb = kt * 32 + quad * 8;
        const float4 a0 = *(const float4*)(xr + kb);
        const float4 a1 = *(const float4*)(xr + kb + 4);
        bf16x8 af;
        af[0] = (short)f32_to_bf16(a0.x); af[1] = (short)f32_to_bf16(a0.y);
        af[2] = (short)f32_to_bf16(a0.z); af[3] = (short)f32_to_bf16(a0.w);
        af[4] = (short)f32_to_bf16(a1.x); af[5] = (short)f32_to_bf16(a1.y);
        af[6] = (short)f32_to_bf16(a1.z); af[7] = (short)f32_to_bf16(a1.w);
        #pragma unroll
        for (int nt = 0; nt < 4; ++nt) {
            const bf16x8 bf = *(const bf16x8*)&b_lds[(nt * 16 + m16) * BK_PAD + kb];
            acc[nt] = __builtin_amdgcn_mfma_f32_16x16x32_bf16(af, bf, acc[nt], 0, 0, 0);
        }
    }
    #pragma unroll
    for (int nt = 0; nt < 4; ++nt) {
        #pragma unroll
        for (int r = 0; r < 4; ++r) {
            const int row = row0 + quad * 4 + r;
            if (row < N_NODES)
                support[(size_t)row * OUT_F + nt * 16 + m16] = f32_to_bf16(acc[nt][r]);
        }
    }
}
__global__ __launch_bounds__(256) void init_out_kernel(const float* __restrict__ bias,
                                                       float* __restrict__ out) {
    const size_t i = (size_t)blockIdx.x * 256 + threadIdx.x;
    if (i < (size_t)N_NODES * OUT_F) out[i] = bias[i & 63];
}
__global__ __launch_bounds__(256) void scatter_atomic_kernel(
    const unsigned short* __restrict__ support, const int* __restrict__ erow,
    const int* __restrict__ ecol, const float* __restrict__ evals,
    float* __restrict__ out) {
    const int wid = (blockIdx.x * 256 + threadIdx.x) >> 6;
    const int nw = gridDim.x * 4;
    const int lane = threadIdx.x & 63;
    const int n_iters = N_EDGES / 8;
    for (int it0 = wid; it0 < n_iters; it0 += nw) {
        const int e0 = __builtin_amdgcn_readfirstlane(it0) * 8;
        int src[8], dst[8]; float val[8];
        #pragma unroll
        for (int u = 0; u < 8; ++u) { src[u] = ecol[e0 + u]; dst[u] = erow[e0 + u]; val[u] = evals[e0 + u]; }
        float g[8];
        #pragma unroll
        for (int u = 0; u < 8; ++u) g[u] = bf16_to_f32(support[(size_t)src[u] * OUT_F + lane]);
        #pragma unroll
        for (int u = 0; u < 8; ++u) atomicAdd(&out[(size_t)dst[u] * OUT_F + lane], g[u] * val[u]);
    }
}

extern "C" void kernel_launch(void* const* d_in, const int* in_sizes, int n_in,
                              void* d_out, int out_size, void* d_ws, size_t ws_size,
                              hipStream_t stream) {
    const float* x     = (const float*)d_in[0];
    const float* w     = (const float*)d_in[1];
    const float* bias  = (const float*)d_in[2];
    const int* erow    = (const int*)d_in[3];
    const int* ecol    = (const int*)d_in[4];
    const float* evals = (const float*)d_in[5];
    float* out = (float*)d_out;

    char* p = (char*)d_ws;
    unsigned short* support = (unsigned short*)p;  size_t o = (size_t)N_NODES * OUT_F * 2;   // 12.8 MB
    int* pos_g = (int*)(p + o);                    o += (size_t)NCHUNK * NPOS * 4;            // 3.2 MB
    uint2* sedge = (uint2*)(p + o);                o += (size_t)N_EDGES * 8;                  // 12.8 MB

    if (ws_size >= o) {
        gemm_sort_kernel<<<NCHUNK + GEMM_BLKS, 512, 0, stream>>>(
            x, w, support, erow, ecol, evals, pos_g, sedge);
        gather_kernel<<<NBUCKET, 512, 0, stream>>>(support, sedge, pos_g, bias, out);
    } else {
        gemm_kernel<<<(N_NODES + 63) / 64, 256, 0, stream>>>(x, w, support);
        init_out_kernel<<<((N_NODES * OUT_F) + 255) / 256, 256, 0, stream>>>(bias, out);
        scatter_atomic_kernel<<<2048, 256, 0, stream>>>(support, erow, ecol, evals, out);
    }
}